// Round 4
// baseline (8242.643 us; speedup 1.0000x reference)
//
#include <hip/hip_runtime.h>
#include <hip/hip_cooperative_groups.h>
#include <math.h>

namespace cg = cooperative_groups;

#define B_N   128
#define M_N   248
#define C_N   248
#define NODES 256
#define NT    (B_N*NODES)     // 32,768
#define NG    (B_N*M_N*C_N)   // 7,872,512

#define GRID  256             // 1 block per CU
#define TPB   512             // 8 waves
#define HROWS 124             // rows per block (half batch)
#define KMAX  16              // rows per wave: lr = wave + 8*k
#define DYN_LDS (KMAX*TPB*16) // vG: [KMAX][TPB] float4 = 131072 B

#define PI_F     3.14159265358979323846f
#define INV_BM   (1.0f/31744.0f)
#define INV_BMC  (1.0f/7872512.0f)

__device__ __forceinline__ float rcp_nr(float x) {
    float r = __builtin_amdgcn_rcpf(x);
    return r * fmaf(-x, r, 2.0f);           // one NR step: ~fp32-accurate
}
__device__ __forceinline__ float sigm_fast(float x) {
    return rcp_nr(1.0f + __expf(-x));
}
__device__ __forceinline__ float sigm(float x) {   // precise (fallback path)
    float z = expf(-fabsf(x));
    return (x >= 0.0f) ? 1.0f/(1.0f+z) : z/(1.0f+z);
}
__device__ __forceinline__ float sgn(float x) {
    return (x > 0.0f) ? 1.0f : ((x < 0.0f) ? -1.0f : 0.0f);
}

// ===================== persistent cooperative path =====================
// 256 blocks x 512 threads, 1 block/CU. Gl+m in VGPRs (128/lane), v in
// 128 KiB dynamic LDS, T/mT/vT in static LDS. Lane owns 4 consecutive
// columns (float4 global/LDS ops). amdgpu_waves_per_eu(2,2) pins the VGPR
// budget at 256 so state is NOT spilled (round-3 failure mode).
extern __shared__ float4 vG_lds[];

__global__ __launch_bounds__(TPB) __attribute__((amdgpu_waves_per_eu(2, 2)))
void persist_kernel(
    const float* __restrict__ adj, const float* __restrict__ Gl0,
    const float* __restrict__ T0,
    float* __restrict__ gTu,    // [2][B_N][M_N]
    float* __restrict__ gTv,    // [2][B_N*16][256]  slice = b*16 + h*8 + wave
    float* __restrict__ accum,  // [2]
    float* __restrict__ out)    // [3]
{
    __shared__ float T_lds[NODES], mT_lds[NODES], vT_lds[NODES];
    __shared__ float red[16];

    cg::grid_group grid = cg::this_grid();
    const int tid  = threadIdx.x;
    const int blkI = blockIdx.x;
    // XCD-pair swizzle: blocks blkI and blkI+8 (same XCD slot) share a batch
    const int b    = ((blkI >> 4) << 3) | (blkI & 7);
    const int h    = (blkI >> 3) & 1;
    const int wave = tid >> 6, lane = tid & 63;
    const bool v62 = (lane < 62);            // lane owns cols 4*lane..4*lane+3
    const int jb   = v62 ? 4*lane : 0;       // clamped col base

    if (tid < NODES) {
        T_lds[tid]  = T0[b*NODES + tid];
        mT_lds[tid] = 0.0f;
        vT_lds[tid] = 0.0f;
    }
    #pragma unroll
    for (int k = 0; k < KMAX; ++k)
        vG_lds[k*TPB + tid] = float4{0.0f, 0.0f, 0.0f, 0.0f};

    float Glr[KMAX][4], mGr[KMAX][4];
    #pragma unroll
    for (int k = 0; k < KMAX; ++k) {
        #pragma unroll
        for (int s = 0; s < 4; ++s) { Glr[k][s] = 0.0f; mGr[k][s] = 0.0f; }
        const int lr = wave + 8*k;
        if (lr < HROWS && v62) {
            const int i = h*HROWS + lr;
            const float4 g4 = *(const float4*)&Gl0[((size_t)(b*M_N + i))*C_N + jb];
            Glr[k][0] = g4.x; Glr[k][1] = g4.y; Glr[k][2] = g4.z; Glr[k][3] = g4.w;
        }
    }
    __syncthreads();

    double pw1d = 1.0, pw2d = 1.0;   // 0.9^(t-1), 0.999^(t-1)
    #pragma unroll 1
    for (int t = 1; t <= 200; ++t) {
        const float bc1p = (float)(1.0 - pw1d), bc2p = (float)(1.0 - pw2d);
        pw1d *= 0.9; pw2d *= 0.999;
        const float bc1 = (float)(1.0 - pw1d), bc2 = (float)(1.0 - pw2d);
        const float ibc1 = 1.0f/bc1, ibc2 = 1.0f/bc2;
        const int pw = t & 1, ps = (t-1) & 1;

        if (t > 1) {                 // grid-uniform
            grid.sync();
            if (tid < NODES) {       // T Adam update for step t-1 (redundant/block)
                float g = 0.0f;
                if (tid < M_N) g += gTu[ps*(B_N*M_N) + b*M_N + tid];
                if (tid >= 8) {
                    const float* gp = gTv + (size_t)ps*(B_N*16*256)
                                    + (size_t)(b*16)*256 + (tid-8);
                    float s = 0.0f;
                    #pragma unroll
                    for (int p = 0; p < 16; ++p) s += gp[p*256];
                    g -= s;
                }
                g *= INV_BMC;
                float m_ = 0.9f*mT_lds[tid] + 0.1f*g;
                float v_ = 0.999f*vT_lds[tid] + 0.001f*(g*g);
                mT_lds[tid] = m_; vT_lds[tid] = v_;
                T_lds[tid] = T_lds[tid] - 0.1f*(m_/bc1p)/(sqrtf(v_/bc2p) + 1e-8f);
            }
            __syncthreads();
        }

        // hoisted T_v values (cols jb..jb+3 -> nodes jb+8..jb+11)
        const float Tv0 = T_lds[jb+8],  Tv1 = T_lds[jb+9];
        const float Tv2 = T_lds[jb+10], Tv3 = T_lds[jb+11];

        float av0 = 0.0f, av1 = 0.0f, av2 = 0.0f, av3 = 0.0f;
        #pragma unroll
        for (int k = 0; k < KMAX; ++k) {
            const int lr = wave + 8*k;       // wave-uniform guard
            if (lr < HROWS) {
                const int i = h*HROWS + lr;
                float4 a4 = {0.0f, 0.0f, 0.0f, 0.0f};
                if (v62)
                    a4 = *(const float4*)&adj[((size_t)(b*NODES + i))*NODES + 8 + jb];

                const float G0 = sigm_fast(Glr[k][0]), G1 = sigm_fast(Glr[k][1]);
                const float G2 = sigm_fast(Glr[k][2]), G3 = sigm_fast(Glr[k][3]);

                const float Tu = T_lds[i];
                const float d0 = v62 ? (Tu - Tv0 + 0.1f) : 0.0f;
                const float d1 = v62 ? (Tu - Tv1 + 0.1f) : 0.0f;
                const float d2 = v62 ? (Tu - Tv2 + 0.1f) : 0.0f;
                const float d3 = v62 ? (Tu - Tv3 + 0.1f) : 0.0f;
                const float p0 = fmaxf(d0,0.0f), p1 = fmaxf(d1,0.0f);
                const float p2 = fmaxf(d2,0.0f), p3 = fmaxf(d3,0.0f);
                const float mk0 = (d0>0.0f)?1.0f:0.0f;
                const float mk1 = (d1>0.0f)?1.0f:0.0f;
                const float mk2 = (d2>0.0f)?1.0f:0.0f;
                const float mk3 = (d3>0.0f)?1.0f:0.0f;

                float sp = a4.x*G0 + a4.y*G1 + a4.z*G2 + a4.w*G3;
                float gu = G0*mk0 + G1*mk1 + G2*mk2 + G3*mk3;
                #pragma unroll
                for (int off = 32; off > 0; off >>= 1) {
                    sp += __shfl_xor(sp, off, 64);
                    gu += __shfl_xor(gu, off, 64);
                }
                av0 += G0*mk0; av1 += G1*mk1; av2 += G2*mk2; av3 += G3*mk3;

                const float half_arg = (PI_F*sp)*0.5f;
                const float sv = __sinf(half_arg), cv = __cosf(half_arg);
                const float coefP = 2.0f*(sv*sv-1.0f)*sv*cv*PI_F*INV_BM;

                if (lane == 0) gTu[pw*(B_N*M_N) + b*M_N + i] = gu;

                float4 vv = vG_lds[k*TPB + tid];
                #define DO_SLOT(Gx, ax, px, vx, s_) do {                             \
                    float dG  = coefP*(ax) + (px)*INV_BMC + 0.1f*INV_BMC*sgn((Gx)-0.5f); \
                    float grd = dG * (Gx) * (1.0f - (Gx));                           \
                    float m_ = 0.9f*mGr[k][s_] + 0.1f*grd;                           \
                    float v_ = 0.999f*(vx) + 0.001f*(grd*grd);                       \
                    mGr[k][s_] = m_; (vx) = v_;                                      \
                    Glr[k][s_] -= 0.1f*(m_*ibc1)*rcp_nr(sqrtf(v_*ibc2) + 1e-8f);     \
                } while (0)
                DO_SLOT(G0, a4.x, p0, vv.x, 0);
                DO_SLOT(G1, a4.y, p1, vv.y, 1);
                DO_SLOT(G2, a4.z, p2, vv.z, 2);
                DO_SLOT(G3, a4.w, p3, vv.w, 3);
                #undef DO_SLOT
                vG_lds[k*TPB + tid] = vv;
            }
        }
        // per-wave gTv column-partial slice (cols 4*lane..4*lane+3; 62/63 -> zeros)
        {
            float* gpw = gTv + (size_t)pw*(B_N*16*256) + (size_t)(b*16 + h*8 + wave)*256;
            ((float4*)gpw)[lane] = float4{av0, av1, av2, av3};
        }
    }

    // ---------------- final T update (step 200; parity slot 0) ----------------
    grid.sync();
    if (tid < NODES) {
        const float bc1p = (float)(1.0 - pw1d), bc2p = (float)(1.0 - pw2d);
        float g = 0.0f;
        if (tid < M_N) g += gTu[0*(B_N*M_N) + b*M_N + tid];
        if (tid >= 8) {
            const float* gp = gTv + (size_t)(b*16)*256 + (tid-8);
            float s = 0.0f;
            #pragma unroll
            for (int p = 0; p < 16; ++p) s += gp[p*256];
            g -= s;
        }
        g *= INV_BMC;
        float m_ = 0.9f*mT_lds[tid] + 0.1f*g;
        float v_ = 0.999f*vT_lds[tid] + 0.001f*(g*g);
        T_lds[tid] = T_lds[tid] - 0.1f*(m_/bc1p)/(sqrtf(v_/bc2p) + 1e-8f);
    }
    __syncthreads();

    // ---------------- final losses ----------------
    {
        const float Tv0 = T_lds[jb+8],  Tv1 = T_lds[jb+9];
        const float Tv2 = T_lds[jb+10], Tv3 = T_lds[jb+11];
        float pacc = 0.0f, cacc = 0.0f;
        #pragma unroll
        for (int k = 0; k < KMAX; ++k) {
            const int lr = wave + 8*k;
            if (lr < HROWS) {
                const int i = h*HROWS + lr;
                float4 a4 = {0.0f, 0.0f, 0.0f, 0.0f};
                if (v62)
                    a4 = *(const float4*)&adj[((size_t)(b*NODES + i))*NODES + 8 + jb];
                const float G0 = sigm_fast(Glr[k][0]), G1 = sigm_fast(Glr[k][1]);
                const float G2 = sigm_fast(Glr[k][2]), G3 = sigm_fast(Glr[k][3]);
                const float Tu = T_lds[i];
                const float p0 = v62 ? fmaxf(Tu - Tv0 + 0.1f, 0.0f) : 0.0f;
                const float p1 = v62 ? fmaxf(Tu - Tv1 + 0.1f, 0.0f) : 0.0f;
                const float p2 = v62 ? fmaxf(Tu - Tv2 + 0.1f, 0.0f) : 0.0f;
                const float p3 = v62 ? fmaxf(Tu - Tv3 + 0.1f, 0.0f) : 0.0f;

                float sp = a4.x*G0 + a4.y*G1 + a4.z*G2 + a4.w*G3;
                float cp = G0*p0 + G1*p1 + G2*p2 + G3*p3;
                #pragma unroll
                for (int off = 32; off > 0; off >>= 1) {
                    sp += __shfl_xor(sp, off, 64);
                    cp += __shfl_xor(cp, off, 64);
                }
                if (lane == 0) {
                    const float sv = sinf((PI_F*sp)*0.5f);
                    const float dd = sv*sv - 1.0f;
                    pacc += dd*dd;
                    cacc += cp;
                }
            }
        }
        if (lane == 0) { red[wave] = pacc; red[8+wave] = cacc; }
    }
    __syncthreads();
    if (tid == 0) {
        float rp = 0.0f, rc = 0.0f;
        #pragma unroll
        for (int w = 0; w < 8; ++w) { rp += red[w]; rc += red[8+w]; }
        atomicAdd(&accum[0], rp);
        atomicAdd(&accum[1], rc);
    }
    __threadfence();
    grid.sync();
    if (blkI == 0 && tid == 0) {
        const float p = __hip_atomic_load(&accum[0], __ATOMIC_RELAXED, __HIP_MEMORY_SCOPE_AGENT) * INV_BM;
        const float c = __hip_atomic_load(&accum[1], __ATOMIC_RELAXED, __HIP_MEMORY_SCOPE_AGENT) * INV_BMC;
        out[0] = p + c;
        out[1] = p;
        out[2] = c;
    }
}

// ===================== fallback multi-launch path (round-1, known-good) =====================
#define NBLK  8
#define RPB   31

__global__ __launch_bounds__(256) void iter_kernel(
    const float* __restrict__ adj, float* __restrict__ Gl,
    float* __restrict__ mG, float* __restrict__ vG,
    float* __restrict__ T_state, float* __restrict__ mT, float* __restrict__ vT,
    float* __restrict__ gTu, float* __restrict__ gTv,
    int t, float bc1p, float bc2p, float bc1, float bc2)
{
    __shared__ float T_lds[NODES];
    __shared__ float gv_lds[4*NODES];
    const int tid = threadIdx.x;
    const int b   = blockIdx.x >> 3;
    const int blk = blockIdx.x & 7;

    if (t == 1) {
        T_lds[tid] = T_state[b*NODES + tid];
    } else {
        const int rs = t & 1, ws2 = (t+1) & 1, ps = (t-1) & 1;
        const int idx = b*NODES + tid;
        float Tval = T_state[rs*NT + idx];
        float g = 0.0f;
        if (tid < M_N) g += gTu[ps*(B_N*M_N) + b*M_N + tid];
        if (tid >= 8) {
            const float* gp = gTv + (size_t)ps*(B_N*NBLK*C_N) + (size_t)b*NBLK*C_N + (tid-8);
            float s = 0.0f;
            #pragma unroll
            for (int k = 0; k < NBLK; ++k) s += gp[k*C_N];
            g -= s;
        }
        g *= INV_BMC;
        float m_ = 0.9f*mT[rs*NT+idx] + 0.1f*g;
        float v_ = 0.999f*vT[rs*NT+idx] + 0.001f*(g*g);
        float newT = Tval - 0.1f*(m_/bc1p)/(sqrtf(v_/bc2p) + 1e-8f);
        T_state[ws2*NT+idx] = newT;
        mT[ws2*NT+idx] = m_;
        vT[ws2*NT+idx] = v_;
        T_lds[tid] = newT;
    }
    gv_lds[tid] = 0.0f; gv_lds[256+tid] = 0.0f; gv_lds[512+tid] = 0.0f; gv_lds[768+tid] = 0.0f;
    __syncthreads();

    const int wave = tid >> 6, lane = tid & 63;
    const int pw = t & 1;
    const int j0 = lane, j1 = lane+64, j2 = lane+128, j3 = lane+192;
    const bool v3 = (lane < 56);
    float av0 = 0.0f, av1 = 0.0f, av2 = 0.0f, av3 = 0.0f;

    for (int r = wave; r < RPB; r += 4) {
        const int i = blk*RPB + r;
        const size_t arow = ((size_t)(b*NODES + i))*NODES + 8;
        const size_t grow = ((size_t)(b*M_N + i))*C_N;

        float gl0 = Gl[grow+j0], gl1 = Gl[grow+j1], gl2 = Gl[grow+j2];
        float gl3 = v3 ? Gl[grow+j3] : 0.0f;
        float a0 = adj[arow+j0], a1 = adj[arow+j1], a2 = adj[arow+j2];
        float a3 = v3 ? adj[arow+j3] : 0.0f;
        float G0 = sigm(gl0), G1 = sigm(gl1), G2 = sigm(gl2), G3 = sigm(gl3);

        float Tu = T_lds[i];
        float d0 = Tu - T_lds[j0+8] + 0.1f;
        float d1 = Tu - T_lds[j1+8] + 0.1f;
        float d2 = Tu - T_lds[j2+8] + 0.1f;
        float d3 = v3 ? (Tu - T_lds[j3+8] + 0.1f) : 0.0f;
        float p0 = fmaxf(d0, 0.0f), p1 = fmaxf(d1, 0.0f);
        float p2 = fmaxf(d2, 0.0f), p3 = fmaxf(d3, 0.0f);
        float mk0 = (d0 > 0.0f) ? 1.0f : 0.0f;
        float mk1 = (d1 > 0.0f) ? 1.0f : 0.0f;
        float mk2 = (d2 > 0.0f) ? 1.0f : 0.0f;
        float mk3 = (v3 && d3 > 0.0f) ? 1.0f : 0.0f;

        float sp = a0*G0 + a1*G1 + a2*G2 + (v3 ? a3*G3 : 0.0f);
        float gu = G0*mk0 + G1*mk1 + G2*mk2 + G3*mk3;
        #pragma unroll
        for (int off = 32; off > 0; off >>= 1) {
            sp += __shfl_xor(sp, off, 64);
            gu += __shfl_xor(gu, off, 64);
        }
        av0 += G0*mk0; av1 += G1*mk1; av2 += G2*mk2; av3 += G3*mk3;

        float half_arg = (PI_F*sp)*0.5f;
        float sv = sinf(half_arg), cv = cosf(half_arg);
        float val = sv*sv;
        float coefP = 2.0f*(val-1.0f)*sv*cv*PI_F*INV_BM;

        if (lane == 0) gTu[pw*(B_N*M_N) + b*M_N + i] = gu;

        #define DO_SLOT(Gx, glx, ax, px, jx, valid) do { if (valid) {            \
            float dG  = coefP*(ax) + (px)*INV_BMC + 0.1f*INV_BMC*sgn((Gx)-0.5f); \
            float grd = dG * (Gx) * (1.0f - (Gx));                               \
            float m_ = 0.9f*mG[grow+(jx)] + 0.1f*grd;                            \
            float v_ = 0.999f*vG[grow+(jx)] + 0.001f*(grd*grd);                  \
            mG[grow+(jx)] = m_; vG[grow+(jx)] = v_;                              \
            Gl[grow+(jx)] = (glx) - 0.1f*(m_/bc1)/(sqrtf(v_/bc2)+1e-8f);         \
        } } while (0)
        DO_SLOT(G0, gl0, a0, p0, j0, true);
        DO_SLOT(G1, gl1, a1, p1, j1, true);
        DO_SLOT(G2, gl2, a2, p2, j2, true);
        DO_SLOT(G3, gl3, a3, p3, j3, v3);
        #undef DO_SLOT
    }

    gv_lds[wave*256 + j0] = av0;
    gv_lds[wave*256 + j1] = av1;
    gv_lds[wave*256 + j2] = av2;
    if (v3) gv_lds[wave*256 + j3] = av3;
    __syncthreads();
    if (tid < C_N) {
        float s = gv_lds[tid] + gv_lds[256+tid] + gv_lds[512+tid] + gv_lds[768+tid];
        gTv[(size_t)pw*(B_N*NBLK*C_N) + (size_t)(b*NBLK + blk)*C_N + tid] = s;
    }
}

__global__ __launch_bounds__(256) void t_fin_kernel(
    float* __restrict__ T_state, const float* __restrict__ mT, const float* __restrict__ vT,
    const float* __restrict__ gTu, const float* __restrict__ gTv,
    float bc1p, float bc2p)
{
    const int b = blockIdx.x, tid = threadIdx.x;
    const int idx = b*NODES + tid;
    float Tval = T_state[1*NT + idx];
    float g = 0.0f;
    if (tid < M_N) g += gTu[0*(B_N*M_N) + b*M_N + tid];
    if (tid >= 8) {
        const float* gp = gTv + (size_t)b*NBLK*C_N + (tid-8);
        float s = 0.0f;
        #pragma unroll
        for (int k = 0; k < NBLK; ++k) s += gp[k*C_N];
        g -= s;
    }
    g *= INV_BMC;
    float m_ = 0.9f*mT[1*NT+idx] + 0.1f*g;
    float v_ = 0.999f*vT[1*NT+idx] + 0.001f*(g*g);
    T_state[0*NT+idx] = Tval - 0.1f*(m_/bc1p)/(sqrtf(v_/bc2p) + 1e-8f);
}

__global__ __launch_bounds__(256) void loss_kernel(
    const float* __restrict__ adj, const float* __restrict__ Gl,
    const float* __restrict__ T_state, float* __restrict__ accum)
{
    __shared__ float T_lds[NODES];
    __shared__ float red[8];
    const int tid = threadIdx.x;
    const int b = blockIdx.x >> 3, blk = blockIdx.x & 7;
    T_lds[tid] = T_state[b*NODES + tid];
    __syncthreads();
    const int wave = tid >> 6, lane = tid & 63;
    const int j0 = lane, j1 = lane+64, j2 = lane+128, j3 = lane+192;
    const bool v3 = (lane < 56);
    float pacc = 0.0f, cacc = 0.0f;

    for (int r = wave; r < RPB; r += 4) {
        const int i = blk*RPB + r;
        const size_t arow = ((size_t)(b*NODES + i))*NODES + 8;
        const size_t grow = ((size_t)(b*M_N + i))*C_N;
        float gl0 = Gl[grow+j0], gl1 = Gl[grow+j1], gl2 = Gl[grow+j2];
        float gl3 = v3 ? Gl[grow+j3] : 0.0f;
        float a0 = adj[arow+j0], a1 = adj[arow+j1], a2 = adj[arow+j2];
        float a3 = v3 ? adj[arow+j3] : 0.0f;
        float G0 = sigm(gl0), G1 = sigm(gl1), G2 = sigm(gl2), G3 = sigm(gl3);

        float Tu = T_lds[i];
        float p0 = fmaxf(Tu - T_lds[j0+8] + 0.1f, 0.0f);
        float p1 = fmaxf(Tu - T_lds[j1+8] + 0.1f, 0.0f);
        float p2 = fmaxf(Tu - T_lds[j2+8] + 0.1f, 0.0f);
        float p3 = v3 ? fmaxf(Tu - T_lds[j3+8] + 0.1f, 0.0f) : 0.0f;

        float sp = a0*G0 + a1*G1 + a2*G2 + (v3 ? a3*G3 : 0.0f);
        float cp = G0*p0 + G1*p1 + G2*p2 + (v3 ? G3*p3 : 0.0f);
        #pragma unroll
        for (int off = 32; off > 0; off >>= 1) {
            sp += __shfl_xor(sp, off, 64);
            cp += __shfl_xor(cp, off, 64);
        }
        if (lane == 0) {
            float sv = sinf((PI_F*sp)*0.5f);
            float dd = sv*sv - 1.0f;
            pacc += dd*dd;
            cacc += cp;
        }
    }
    if (lane == 0) { red[wave] = pacc; red[4+wave] = cacc; }
    __syncthreads();
    if (tid == 0) {
        atomicAdd(&accum[0], red[0]+red[1]+red[2]+red[3]);
        atomicAdd(&accum[1], red[4]+red[5]+red[6]+red[7]);
    }
}

__global__ void finish_kernel(const float* __restrict__ accum, float* __restrict__ out) {
    if (threadIdx.x == 0 && blockIdx.x == 0) {
        float p = accum[0] / 31744.0f;
        float c = accum[1] / 7872512.0f;
        out[0] = p + c;
        out[1] = p;
        out[2] = c;
    }
}

extern "C" void kernel_launch(void* const* d_in, const int* in_sizes, int n_in,
                              void* d_out, int out_size, void* d_ws, size_t ws_size,
                              hipStream_t stream) {
    const float* adj = (const float*)d_in[0];
    float* Gl        = (float*)d_in[1];
    const float* T0  = (const float*)d_in[2];
    float* out       = (float*)d_out;
    float* ws        = (float*)d_ws;

    // host-side gate (pure host queries + func attribute; capture-safe)
    int dev = 0;  hipGetDevice(&dev);
    int numCU = 0;
    hipDeviceGetAttribute(&numCU, hipDeviceAttributeMultiprocessorCount, dev);
    hipError_t aerr = hipFuncSetAttribute((const void*)persist_kernel,
                                          hipFuncAttributeMaxDynamicSharedMemorySize,
                                          DYN_LDS);
    int maxB = 0;
    hipError_t oerr = hipOccupancyMaxActiveBlocksPerMultiprocessor(
                          &maxB, persist_kernel, TPB, DYN_LDS);
    const bool coop_ok = (aerr == hipSuccess) && (oerr == hipSuccess) &&
                         (maxB >= 1) && ((long)maxB * (long)numCU >= GRID);

    if (coop_ok) {
        float* gTu   = ws;                               // 2*128*248
        float* gTv   = gTu + 2*B_N*M_N;                  // 2*128*16*256
        float* accum = gTv + (size_t)2*B_N*16*256;       // 2
        hipMemsetAsync(accum, 0, 2*sizeof(float), stream);

        const float* Gl0 = Gl;
        void* args[] = { (void*)&adj, (void*)&Gl0, (void*)&T0,
                         (void*)&gTu, (void*)&gTv, (void*)&accum, (void*)&out };
        hipLaunchCooperativeKernel((void*)persist_kernel,
                                   dim3(GRID), dim3(TPB), args, DYN_LDS, stream);
    } else {
        float* mG      = ws;
        float* vG      = mG + NG;
        float* T_state = vG + NG;
        float* mT      = T_state + 2*NT;
        float* vT      = mT + 2*NT;
        float* gTu     = vT + 2*NT;
        float* gTv     = gTu + 2*B_N*M_N;
        float* accum   = gTv + (size_t)2*B_N*NBLK*C_N;

        hipMemsetAsync(mG, 0, (size_t)2*NG*sizeof(float), stream);
        hipMemsetAsync(mT, 0, (size_t)4*NT*sizeof(float), stream);
        hipMemsetAsync(accum, 0, 2*sizeof(float), stream);
        hipMemcpyAsync(T_state, T0, NT*sizeof(float), hipMemcpyDeviceToDevice, stream);

        for (int t = 1; t <= 200; ++t) {
            float bc1p = 1.0f - (float)pow(0.9,   (double)(t-1));
            float bc2p = 1.0f - (float)pow(0.999, (double)(t-1));
            float bc1  = 1.0f - (float)pow(0.9,   (double)t);
            float bc2  = 1.0f - (float)pow(0.999, (double)t);
            iter_kernel<<<dim3(B_N*NBLK), dim3(256), 0, stream>>>(
                adj, Gl, mG, vG, T_state, mT, vT, gTu, gTv, t, bc1p, bc2p, bc1, bc2);
        }
        {
            float bc1p = 1.0f - (float)pow(0.9,   200.0);
            float bc2p = 1.0f - (float)pow(0.999, 200.0);
            t_fin_kernel<<<dim3(B_N), dim3(256), 0, stream>>>(T_state, mT, vT, gTu, gTv, bc1p, bc2p);
        }
        loss_kernel<<<dim3(B_N*NBLK), dim3(256), 0, stream>>>(adj, Gl, T_state, accum);
        finish_kernel<<<1, 64, 0, stream>>>(accum, out);
    }
}

// Round 5
// 8151.141 us; speedup vs baseline: 1.0112x; 1.0112x over previous
//
#include <hip/hip_runtime.h>
#include <hip/hip_cooperative_groups.h>
#include <math.h>

namespace cg = cooperative_groups;

#define B_N   128
#define M_N   248
#define C_N   248
#define NODES 256
#define NT    (B_N*NODES)     // 32,768
#define NG    (B_N*M_N*C_N)   // 7,872,512

#define GRID  256             // 1 block per CU
#define TPB   1024            // 16 waves -> 4 waves/SIMD -> HW VGPR cap 128 (design point)
#define WAVES 16
#define HROWS 124             // rows per block (half batch)
#define KMAX  8               // row k of a wave: lr = wave + 16*k
#define SLICES 32             // gTv slices per batch: 2 halves * 16 waves
#define DYN_LDS (KMAX*TPB*16) // vG: [KMAX][TPB] float4 = 131072 B

#define PI_F     3.14159265358979323846f
#define INV_BM   (1.0f/31744.0f)
#define INV_BMC  (1.0f/7872512.0f)

__device__ __forceinline__ float rcp_nr(float x) {
    float r = __builtin_amdgcn_rcpf(x);
    return r * fmaf(-x, r, 2.0f);           // one NR step: ~fp32-accurate
}
__device__ __forceinline__ float sigm_fast(float x) {
    return rcp_nr(1.0f + __expf(-x));
}
__device__ __forceinline__ float sigm(float x) {   // precise (fallback path)
    float z = expf(-fabsf(x));
    return (x >= 0.0f) ? 1.0f/(1.0f+z) : z/(1.0f+z);
}
__device__ __forceinline__ float sgn(float x) {
    return (x > 0.0f) ? 1.0f : ((x < 0.0f) ? -1.0f : 0.0f);
}

// ===================== persistent cooperative path =====================
// 256 blocks x 1024 threads (1 block/CU, 16 waves). Per-thread state:
// Gl+m as 16 explicit float4 VGPR variables (64 regs, no arrays -> no
// scratch demotion, the r3/r4 failure), v in 128 KiB dynamic LDS.
// T/mT/vT in static LDS. One grid.sync per iteration; parity-double-
// buffered gTu/gTv partials carry the T gradient across blocks.
extern __shared__ float4 vG_lds[];

__global__ __launch_bounds__(TPB)
void persist_kernel(
    const float* __restrict__ adj, const float* __restrict__ Gl0,
    const float* __restrict__ T0,
    float* __restrict__ gTu,    // [2][B_N][M_N]
    float* __restrict__ gTv,    // [2][B_N*SLICES][256]  slice = b*32 + h*16 + wave
    float* __restrict__ accum,  // [2]
    float* __restrict__ out)    // [3]
{
    __shared__ float T_lds[NODES], mT_lds[NODES], vT_lds[NODES];
    __shared__ float red[2*WAVES];

    cg::grid_group grid = cg::this_grid();
    const int tid  = threadIdx.x;
    const int blkI = blockIdx.x;
    // XCD-pair swizzle: blkI and blkI+8 share a batch
    const int b    = ((blkI >> 4) << 3) | (blkI & 7);
    const int h    = (blkI >> 3) & 1;
    const int wave = tid >> 6, lane = tid & 63;
    const bool v62 = (lane < 62);            // lane owns cols 4*lane..4*lane+3
    const int jb   = v62 ? 4*lane : 0;
    const int iBase = h*HROWS + wave;        // row for slot k: iBase + 16*k
    const float* adjRow0 = adj + ((size_t)(b*NODES + iBase))*NODES + 8 + jb;

    // k<7 always valid (wave+96 <= 111 < 124); k==7 valid iff wave < 12
    #define ROW_OK(k) ((k) < 7 || wave < 12)

    if (tid < NODES) {
        T_lds[tid]  = T0[b*NODES + tid];
        mT_lds[tid] = 0.0f;
        vT_lds[tid] = 0.0f;
    }
    #pragma unroll
    for (int k = 0; k < KMAX; ++k)
        vG_lds[k*TPB + tid] = float4{0.0f, 0.0f, 0.0f, 0.0f};

    float4 gl0, gl1, gl2, gl3, gl4, gl5, gl6, gl7;
    float4 mm0, mm1, mm2, mm3, mm4, mm5, mm6, mm7;
    #define LOADG(k, glv, mmv) do {                                               \
        glv = float4{0.0f,0.0f,0.0f,0.0f}; mmv = float4{0.0f,0.0f,0.0f,0.0f};     \
        if (ROW_OK(k) && v62)                                                     \
            glv = *(const float4*)&Gl0[((size_t)(b*M_N + iBase + 16*(k)))*C_N + jb]; \
    } while (0)
    LOADG(0, gl0, mm0); LOADG(1, gl1, mm1); LOADG(2, gl2, mm2); LOADG(3, gl3, mm3);
    LOADG(4, gl4, mm4); LOADG(5, gl5, mm5); LOADG(6, gl6, mm6); LOADG(7, gl7, mm7);
    #undef LOADG
    __syncthreads();

    double pw1d = 1.0, pw2d = 1.0;   // 0.9^(t-1), 0.999^(t-1)
    #pragma unroll 1
    for (int t = 1; t <= 200; ++t) {
        const float bc1p = (float)(1.0 - pw1d), bc2p = (float)(1.0 - pw2d);
        pw1d *= 0.9; pw2d *= 0.999;
        const float bc1 = (float)(1.0 - pw1d), bc2 = (float)(1.0 - pw2d);
        const float ibc1 = 1.0f/bc1, ibc2 = 1.0f/bc2;
        const int pw = t & 1, ps = (t-1) & 1;

        if (t > 1) {                 // grid-uniform
            grid.sync();
            if (tid < NODES) {       // T Adam update for step t-1 (redundant/block)
                float g = 0.0f;
                if (tid < M_N) g += gTu[ps*(B_N*M_N) + b*M_N + tid];
                if (tid >= 8) {
                    const float* gp = gTv + (size_t)ps*(B_N*SLICES*256)
                                    + (size_t)(b*SLICES)*256 + (tid-8);
                    float s = 0.0f;
                    #pragma unroll
                    for (int p = 0; p < SLICES; ++p) s += gp[p*256];
                    g -= s;
                }
                g *= INV_BMC;
                float m_ = 0.9f*mT_lds[tid] + 0.1f*g;
                float v_ = 0.999f*vT_lds[tid] + 0.001f*(g*g);
                mT_lds[tid] = m_; vT_lds[tid] = v_;
                T_lds[tid] = T_lds[tid] - 0.1f*(m_/bc1p)/(sqrtf(v_/bc2p) + 1e-8f);
            }
            __syncthreads();
        }

        const float Tv0 = T_lds[jb+8],  Tv1 = T_lds[jb+9];
        const float Tv2 = T_lds[jb+10], Tv3 = T_lds[jb+11];
        float av0 = 0.0f, av1 = 0.0f, av2 = 0.0f, av3 = 0.0f;

        #define DO_SLOT(Gx, ax, px, mx, vx) do {                                     \
            float dG  = coefP*(ax) + (px)*INV_BMC + 0.1f*INV_BMC*sgn((Gx)-0.5f);     \
            float grd = dG * (Gx) * (1.0f - (Gx));                                   \
            float m_ = 0.9f*(mx) + 0.1f*grd;                                         \
            float v_ = 0.999f*(vx) + 0.001f*(grd*grd);                               \
            (mx) = m_; (vx) = v_;                                                    \
            glslot -= 0.1f*(m_*ibc1)*rcp_nr(sqrtf(v_*ibc2) + 1e-8f);                 \
        } while (0)

        #define ROW_STEP(k, glv, mmv) do { if (ROW_OK(k)) {                          \
            const int i = iBase + 16*(k);                                            \
            float4 a4 = float4{0.0f,0.0f,0.0f,0.0f};                                 \
            if (v62) a4 = *(const float4*)(adjRow0 + (size_t)(16*(k))*NODES);        \
            const float G0 = sigm_fast(glv.x), G1 = sigm_fast(glv.y);                \
            const float G2 = sigm_fast(glv.z), G3 = sigm_fast(glv.w);                \
            const float Tu = T_lds[i];                                               \
            float d0, d1, d2, d3;                                                    \
            if (v62) { d0 = Tu-Tv0+0.1f; d1 = Tu-Tv1+0.1f;                           \
                       d2 = Tu-Tv2+0.1f; d3 = Tu-Tv3+0.1f; }                         \
            else     { d0 = d1 = d2 = d3 = 0.0f; }                                   \
            const float p0 = fmaxf(d0,0.0f), p1 = fmaxf(d1,0.0f);                    \
            const float p2 = fmaxf(d2,0.0f), p3 = fmaxf(d3,0.0f);                    \
            const float mk0 = (d0>0.0f)?1.0f:0.0f, mk1 = (d1>0.0f)?1.0f:0.0f;        \
            const float mk2 = (d2>0.0f)?1.0f:0.0f, mk3 = (d3>0.0f)?1.0f:0.0f;        \
            float sp = a4.x*G0 + a4.y*G1 + a4.z*G2 + a4.w*G3;                        \
            float gu = G0*mk0 + G1*mk1 + G2*mk2 + G3*mk3;                            \
            sp += __shfl_xor(sp,32,64); gu += __shfl_xor(gu,32,64);                  \
            sp += __shfl_xor(sp,16,64); gu += __shfl_xor(gu,16,64);                  \
            sp += __shfl_xor(sp, 8,64); gu += __shfl_xor(gu, 8,64);                  \
            sp += __shfl_xor(sp, 4,64); gu += __shfl_xor(gu, 4,64);                  \
            sp += __shfl_xor(sp, 2,64); gu += __shfl_xor(gu, 2,64);                  \
            sp += __shfl_xor(sp, 1,64); gu += __shfl_xor(gu, 1,64);                  \
            av0 += G0*mk0; av1 += G1*mk1; av2 += G2*mk2; av3 += G3*mk3;              \
            const float half_arg = (PI_F*sp)*0.5f;                                   \
            const float sv = __sinf(half_arg), cv = __cosf(half_arg);                \
            const float coefP = 2.0f*(sv*sv-1.0f)*sv*cv*PI_F*INV_BM;                 \
            if (lane == 0) gTu[pw*(B_N*M_N) + b*M_N + i] = gu;                       \
            float4 vv = vG_lds[(k)*TPB + tid];                                       \
            { float& glslot = glv.x; DO_SLOT(G0, a4.x, p0, mmv.x, vv.x); }           \
            { float& glslot = glv.y; DO_SLOT(G1, a4.y, p1, mmv.y, vv.y); }           \
            { float& glslot = glv.z; DO_SLOT(G2, a4.z, p2, mmv.z, vv.z); }           \
            { float& glslot = glv.w; DO_SLOT(G3, a4.w, p3, mmv.w, vv.w); }           \
            vG_lds[(k)*TPB + tid] = vv;                                              \
        } } while (0)

        ROW_STEP(0, gl0, mm0); ROW_STEP(1, gl1, mm1);
        ROW_STEP(2, gl2, mm2); ROW_STEP(3, gl3, mm3);
        ROW_STEP(4, gl4, mm4); ROW_STEP(5, gl5, mm5);
        ROW_STEP(6, gl6, mm6); ROW_STEP(7, gl7, mm7);
        #undef ROW_STEP
        #undef DO_SLOT

        // per-wave gTv column-partial slice
        {
            float* gpw = gTv + (size_t)pw*(B_N*SLICES*256)
                       + (size_t)(b*SLICES + h*WAVES + wave)*256;
            ((float4*)gpw)[lane] = float4{av0, av1, av2, av3};
        }
    }

    // ---------------- final T update (step 200; parity slot 0) ----------------
    grid.sync();
    if (tid < NODES) {
        const float bc1p = (float)(1.0 - pw1d), bc2p = (float)(1.0 - pw2d);
        float g = 0.0f;
        if (tid < M_N) g += gTu[0*(B_N*M_N) + b*M_N + tid];
        if (tid >= 8) {
            const float* gp = gTv + (size_t)(b*SLICES)*256 + (tid-8);
            float s = 0.0f;
            #pragma unroll
            for (int p = 0; p < SLICES; ++p) s += gp[p*256];
            g -= s;
        }
        g *= INV_BMC;
        float m_ = 0.9f*mT_lds[tid] + 0.1f*g;
        float v_ = 0.999f*vT_lds[tid] + 0.001f*(g*g);
        T_lds[tid] = T_lds[tid] - 0.1f*(m_/bc1p)/(sqrtf(v_/bc2p) + 1e-8f);
    }
    __syncthreads();

    // ---------------- final losses ----------------
    {
        const float Tv0 = T_lds[jb+8],  Tv1 = T_lds[jb+9];
        const float Tv2 = T_lds[jb+10], Tv3 = T_lds[jb+11];
        float pacc = 0.0f, cacc = 0.0f;

        #define ROW_LOSS(k, glv) do { if (ROW_OK(k)) {                               \
            const int i = iBase + 16*(k);                                            \
            float4 a4 = float4{0.0f,0.0f,0.0f,0.0f};                                 \
            if (v62) a4 = *(const float4*)(adjRow0 + (size_t)(16*(k))*NODES);        \
            const float G0 = sigm_fast(glv.x), G1 = sigm_fast(glv.y);                \
            const float G2 = sigm_fast(glv.z), G3 = sigm_fast(glv.w);                \
            const float Tu = T_lds[i];                                               \
            const float p0 = v62 ? fmaxf(Tu-Tv0+0.1f, 0.0f) : 0.0f;                  \
            const float p1 = v62 ? fmaxf(Tu-Tv1+0.1f, 0.0f) : 0.0f;                  \
            const float p2 = v62 ? fmaxf(Tu-Tv2+0.1f, 0.0f) : 0.0f;                  \
            const float p3 = v62 ? fmaxf(Tu-Tv3+0.1f, 0.0f) : 0.0f;                  \
            float sp = a4.x*G0 + a4.y*G1 + a4.z*G2 + a4.w*G3;                        \
            float cp = G0*p0 + G1*p1 + G2*p2 + G3*p3;                                \
            sp += __shfl_xor(sp,32,64); cp += __shfl_xor(cp,32,64);                  \
            sp += __shfl_xor(sp,16,64); cp += __shfl_xor(cp,16,64);                  \
            sp += __shfl_xor(sp, 8,64); cp += __shfl_xor(cp, 8,64);                  \
            sp += __shfl_xor(sp, 4,64); cp += __shfl_xor(cp, 4,64);                  \
            sp += __shfl_xor(sp, 2,64); cp += __shfl_xor(cp, 2,64);                  \
            sp += __shfl_xor(sp, 1,64); cp += __shfl_xor(cp, 1,64);                  \
            if (lane == 0) {                                                         \
                const float sv = sinf((PI_F*sp)*0.5f);                               \
                const float dd = sv*sv - 1.0f;                                       \
                pacc += dd*dd;                                                       \
                cacc += cp;                                                          \
            }                                                                        \
        } } while (0)

        ROW_LOSS(0, gl0); ROW_LOSS(1, gl1); ROW_LOSS(2, gl2); ROW_LOSS(3, gl3);
        ROW_LOSS(4, gl4); ROW_LOSS(5, gl5); ROW_LOSS(6, gl6); ROW_LOSS(7, gl7);
        #undef ROW_LOSS

        if (lane == 0) { red[wave] = pacc; red[WAVES+wave] = cacc; }
    }
    __syncthreads();
    if (tid == 0) {
        float rp = 0.0f, rc = 0.0f;
        #pragma unroll
        for (int w = 0; w < WAVES; ++w) { rp += red[w]; rc += red[WAVES+w]; }
        atomicAdd(&accum[0], rp);
        atomicAdd(&accum[1], rc);
    }
    __threadfence();
    grid.sync();
    if (blkI == 0 && tid == 0) {
        const float p = __hip_atomic_load(&accum[0], __ATOMIC_RELAXED, __HIP_MEMORY_SCOPE_AGENT) * INV_BM;
        const float c = __hip_atomic_load(&accum[1], __ATOMIC_RELAXED, __HIP_MEMORY_SCOPE_AGENT) * INV_BMC;
        out[0] = p + c;
        out[1] = p;
        out[2] = c;
    }
    #undef ROW_OK
}

// ===================== fallback multi-launch path (round-1, known-good) =====================
#define NBLK  8
#define RPB   31

__global__ __launch_bounds__(256) void iter_kernel(
    const float* __restrict__ adj, float* __restrict__ Gl,
    float* __restrict__ mG, float* __restrict__ vG,
    float* __restrict__ T_state, float* __restrict__ mT, float* __restrict__ vT,
    float* __restrict__ gTu, float* __restrict__ gTv,
    int t, float bc1p, float bc2p, float bc1, float bc2)
{
    __shared__ float T_lds[NODES];
    __shared__ float gv_lds[4*NODES];
    const int tid = threadIdx.x;
    const int b   = blockIdx.x >> 3;
    const int blk = blockIdx.x & 7;

    if (t == 1) {
        T_lds[tid] = T_state[b*NODES + tid];
    } else {
        const int rs = t & 1, ws2 = (t+1) & 1, ps = (t-1) & 1;
        const int idx = b*NODES + tid;
        float Tval = T_state[rs*NT + idx];
        float g = 0.0f;
        if (tid < M_N) g += gTu[ps*(B_N*M_N) + b*M_N + tid];
        if (tid >= 8) {
            const float* gp = gTv + (size_t)ps*(B_N*NBLK*C_N) + (size_t)b*NBLK*C_N + (tid-8);
            float s = 0.0f;
            #pragma unroll
            for (int k = 0; k < NBLK; ++k) s += gp[k*C_N];
            g -= s;
        }
        g *= INV_BMC;
        float m_ = 0.9f*mT[rs*NT+idx] + 0.1f*g;
        float v_ = 0.999f*vT[rs*NT+idx] + 0.001f*(g*g);
        float newT = Tval - 0.1f*(m_/bc1p)/(sqrtf(v_/bc2p) + 1e-8f);
        T_state[ws2*NT+idx] = newT;
        mT[ws2*NT+idx] = m_;
        vT[ws2*NT+idx] = v_;
        T_lds[tid] = newT;
    }
    gv_lds[tid] = 0.0f; gv_lds[256+tid] = 0.0f; gv_lds[512+tid] = 0.0f; gv_lds[768+tid] = 0.0f;
    __syncthreads();

    const int wave = tid >> 6, lane = tid & 63;
    const int pw = t & 1;
    const int j0 = lane, j1 = lane+64, j2 = lane+128, j3 = lane+192;
    const bool v3 = (lane < 56);
    float av0 = 0.0f, av1 = 0.0f, av2 = 0.0f, av3 = 0.0f;

    for (int r = wave; r < RPB; r += 4) {
        const int i = blk*RPB + r;
        const size_t arow = ((size_t)(b*NODES + i))*NODES + 8;
        const size_t grow = ((size_t)(b*M_N + i))*C_N;

        float gl0 = Gl[grow+j0], gl1 = Gl[grow+j1], gl2 = Gl[grow+j2];
        float gl3 = v3 ? Gl[grow+j3] : 0.0f;
        float a0 = adj[arow+j0], a1 = adj[arow+j1], a2 = adj[arow+j2];
        float a3 = v3 ? adj[arow+j3] : 0.0f;
        float G0 = sigm(gl0), G1 = sigm(gl1), G2 = sigm(gl2), G3 = sigm(gl3);

        float Tu = T_lds[i];
        float d0 = Tu - T_lds[j0+8] + 0.1f;
        float d1 = Tu - T_lds[j1+8] + 0.1f;
        float d2 = Tu - T_lds[j2+8] + 0.1f;
        float d3 = v3 ? (Tu - T_lds[j3+8] + 0.1f) : 0.0f;
        float p0 = fmaxf(d0, 0.0f), p1 = fmaxf(d1, 0.0f);
        float p2 = fmaxf(d2, 0.0f), p3 = fmaxf(d3, 0.0f);
        float mk0 = (d0 > 0.0f) ? 1.0f : 0.0f;
        float mk1 = (d1 > 0.0f) ? 1.0f : 0.0f;
        float mk2 = (d2 > 0.0f) ? 1.0f : 0.0f;
        float mk3 = (v3 && d3 > 0.0f) ? 1.0f : 0.0f;

        float sp = a0*G0 + a1*G1 + a2*G2 + (v3 ? a3*G3 : 0.0f);
        float gu = G0*mk0 + G1*mk1 + G2*mk2 + G3*mk3;
        #pragma unroll
        for (int off = 32; off > 0; off >>= 1) {
            sp += __shfl_xor(sp, off, 64);
            gu += __shfl_xor(gu, off, 64);
        }
        av0 += G0*mk0; av1 += G1*mk1; av2 += G2*mk2; av3 += G3*mk3;

        float half_arg = (PI_F*sp)*0.5f;
        float sv = sinf(half_arg), cv = cosf(half_arg);
        float val = sv*sv;
        float coefP = 2.0f*(val-1.0f)*sv*cv*PI_F*INV_BM;

        if (lane == 0) gTu[pw*(B_N*M_N) + b*M_N + i] = gu;

        #define DO_SLOT(Gx, glx, ax, px, jx, valid) do { if (valid) {            \
            float dG  = coefP*(ax) + (px)*INV_BMC + 0.1f*INV_BMC*sgn((Gx)-0.5f); \
            float grd = dG * (Gx) * (1.0f - (Gx));                               \
            float m_ = 0.9f*mG[grow+(jx)] + 0.1f*grd;                            \
            float v_ = 0.999f*vG[grow+(jx)] + 0.001f*(grd*grd);                  \
            mG[grow+(jx)] = m_; vG[grow+(jx)] = v_;                              \
            Gl[grow+(jx)] = (glx) - 0.1f*(m_/bc1)/(sqrtf(v_/bc2)+1e-8f);         \
        } } while (0)
        DO_SLOT(G0, gl0, a0, p0, j0, true);
        DO_SLOT(G1, gl1, a1, p1, j1, true);
        DO_SLOT(G2, gl2, a2, p2, j2, true);
        DO_SLOT(G3, gl3, a3, p3, j3, v3);
        #undef DO_SLOT
    }

    gv_lds[wave*256 + j0] = av0;
    gv_lds[wave*256 + j1] = av1;
    gv_lds[wave*256 + j2] = av2;
    if (v3) gv_lds[wave*256 + j3] = av3;
    __syncthreads();
    if (tid < C_N) {
        float s = gv_lds[tid] + gv_lds[256+tid] + gv_lds[512+tid] + gv_lds[768+tid];
        gTv[(size_t)pw*(B_N*NBLK*C_N) + (size_t)(b*NBLK + blk)*C_N + tid] = s;
    }
}

__global__ __launch_bounds__(256) void t_fin_kernel(
    float* __restrict__ T_state, const float* __restrict__ mT, const float* __restrict__ vT,
    const float* __restrict__ gTu, const float* __restrict__ gTv,
    float bc1p, float bc2p)
{
    const int b = blockIdx.x, tid = threadIdx.x;
    const int idx = b*NODES + tid;
    float Tval = T_state[1*NT + idx];
    float g = 0.0f;
    if (tid < M_N) g += gTu[0*(B_N*M_N) + b*M_N + tid];
    if (tid >= 8) {
        const float* gp = gTv + (size_t)b*NBLK*C_N + (tid-8);
        float s = 0.0f;
        #pragma unroll
        for (int k = 0; k < NBLK; ++k) s += gp[k*C_N];
        g -= s;
    }
    g *= INV_BMC;
    float m_ = 0.9f*mT[1*NT+idx] + 0.1f*g;
    float v_ = 0.999f*vT[1*NT+idx] + 0.001f*(g*g);
    T_state[0*NT+idx] = Tval - 0.1f*(m_/bc1p)/(sqrtf(v_/bc2p) + 1e-8f);
}

__global__ __launch_bounds__(256) void loss_kernel(
    const float* __restrict__ adj, const float* __restrict__ Gl,
    const float* __restrict__ T_state, float* __restrict__ accum)
{
    __shared__ float T_lds[NODES];
    __shared__ float red[8];
    const int tid = threadIdx.x;
    const int b = blockIdx.x >> 3, blk = blockIdx.x & 7;
    T_lds[tid] = T_state[b*NODES + tid];
    __syncthreads();
    const int wave = tid >> 6, lane = tid & 63;
    const int j0 = lane, j1 = lane+64, j2 = lane+128, j3 = lane+192;
    const bool v3 = (lane < 56);
    float pacc = 0.0f, cacc = 0.0f;

    for (int r = wave; r < RPB; r += 4) {
        const int i = blk*RPB + r;
        const size_t arow = ((size_t)(b*NODES + i))*NODES + 8;
        const size_t grow = ((size_t)(b*M_N + i))*C_N;
        float gl0 = Gl[grow+j0], gl1 = Gl[grow+j1], gl2 = Gl[grow+j2];
        float gl3 = v3 ? Gl[grow+j3] : 0.0f;
        float a0 = adj[arow+j0], a1 = adj[arow+j1], a2 = adj[arow+j2];
        float a3 = v3 ? adj[arow+j3] : 0.0f;
        float G0 = sigm(gl0), G1 = sigm(gl1), G2 = sigm(gl2), G3 = sigm(gl3);

        float Tu = T_lds[i];
        float p0 = fmaxf(Tu - T_lds[j0+8] + 0.1f, 0.0f);
        float p1 = fmaxf(Tu - T_lds[j1+8] + 0.1f, 0.0f);
        float p2 = fmaxf(Tu - T_lds[j2+8] + 0.1f, 0.0f);
        float p3 = v3 ? fmaxf(Tu - T_lds[j3+8] + 0.1f, 0.0f) : 0.0f;

        float sp = a0*G0 + a1*G1 + a2*G2 + (v3 ? a3*G3 : 0.0f);
        float cp = G0*p0 + G1*p1 + G2*p2 + (v3 ? G3*p3 : 0.0f);
        #pragma unroll
        for (int off = 32; off > 0; off >>= 1) {
            sp += __shfl_xor(sp, off, 64);
            cp += __shfl_xor(cp, off, 64);
        }
        if (lane == 0) {
            float sv = sinf((PI_F*sp)*0.5f);
            float dd = sv*sv - 1.0f;
            pacc += dd*dd;
            cacc += cp;
        }
    }
    if (lane == 0) { red[wave] = pacc; red[4+wave] = cacc; }
    __syncthreads();
    if (tid == 0) {
        atomicAdd(&accum[0], red[0]+red[1]+red[2]+red[3]);
        atomicAdd(&accum[1], red[4]+red[5]+red[6]+red[7]);
    }
}

__global__ void finish_kernel(const float* __restrict__ accum, float* __restrict__ out) {
    if (threadIdx.x == 0 && blockIdx.x == 0) {
        float p = accum[0] / 31744.0f;
        float c = accum[1] / 7872512.0f;
        out[0] = p + c;
        out[1] = p;
        out[2] = c;
    }
}

extern "C" void kernel_launch(void* const* d_in, const int* in_sizes, int n_in,
                              void* d_out, int out_size, void* d_ws, size_t ws_size,
                              hipStream_t stream) {
    const float* adj = (const float*)d_in[0];
    float* Gl        = (float*)d_in[1];
    const float* T0  = (const float*)d_in[2];
    float* out       = (float*)d_out;
    float* ws        = (float*)d_ws;

    // host-side gate (pure host queries + func attribute; capture-safe)
    int dev = 0;  hipGetDevice(&dev);
    int numCU = 0;
    hipDeviceGetAttribute(&numCU, hipDeviceAttributeMultiprocessorCount, dev);
    hipError_t aerr = hipFuncSetAttribute((const void*)persist_kernel,
                                          hipFuncAttributeMaxDynamicSharedMemorySize,
                                          DYN_LDS);
    int maxB = 0;
    hipError_t oerr = hipOccupancyMaxActiveBlocksPerMultiprocessor(
                          &maxB, persist_kernel, TPB, DYN_LDS);
    const bool coop_ok = (aerr == hipSuccess) && (oerr == hipSuccess) &&
                         (maxB >= 1) && ((long)maxB * (long)numCU >= GRID);

    if (coop_ok) {
        float* gTu   = ws;                               // 2*128*248
        float* gTv   = gTu + 2*B_N*M_N;                  // 2*128*32*256
        float* accum = gTv + (size_t)2*B_N*SLICES*256;   // 2
        hipMemsetAsync(accum, 0, 2*sizeof(float), stream);

        const float* Gl0 = Gl;
        void* args[] = { (void*)&adj, (void*)&Gl0, (void*)&T0,
                         (void*)&gTu, (void*)&gTv, (void*)&accum, (void*)&out };
        hipLaunchCooperativeKernel((void*)persist_kernel,
                                   dim3(GRID), dim3(TPB), args, DYN_LDS, stream);
    } else {
        float* mG      = ws;
        float* vG      = mG + NG;
        float* T_state = vG + NG;
        float* mT      = T_state + 2*NT;
        float* vT      = mT + 2*NT;
        float* gTu     = vT + 2*NT;
        float* gTv     = gTu + 2*B_N*M_N;
        float* accum   = gTv + (size_t)2*B_N*NBLK*C_N;

        hipMemsetAsync(mG, 0, (size_t)2*NG*sizeof(float), stream);
        hipMemsetAsync(mT, 0, (size_t)4*NT*sizeof(float), stream);
        hipMemsetAsync(accum, 0, 2*sizeof(float), stream);
        hipMemcpyAsync(T_state, T0, NT*sizeof(float), hipMemcpyDeviceToDevice, stream);

        for (int t = 1; t <= 200; ++t) {
            float bc1p = 1.0f - (float)pow(0.9,   (double)(t-1));
            float bc2p = 1.0f - (float)pow(0.999, (double)(t-1));
            float bc1  = 1.0f - (float)pow(0.9,   (double)t);
            float bc2  = 1.0f - (float)pow(0.999, (double)t);
            iter_kernel<<<dim3(B_N*NBLK), dim3(256), 0, stream>>>(
                adj, Gl, mG, vG, T_state, mT, vT, gTu, gTv, t, bc1p, bc2p, bc1, bc2);
        }
        {
            float bc1p = 1.0f - (float)pow(0.9,   200.0);
            float bc2p = 1.0f - (float)pow(0.999, 200.0);
            t_fin_kernel<<<dim3(B_N), dim3(256), 0, stream>>>(T_state, mT, vT, gTu, gTv, bc1p, bc2p);
        }
        loss_kernel<<<dim3(B_N*NBLK), dim3(256), 0, stream>>>(adj, Gl, T_state, accum);
        finish_kernel<<<1, 64, 0, stream>>>(accum, out);
    }
}

// Round 6
// 8143.835 us; speedup vs baseline: 1.0121x; 1.0009x over previous
//
#include <hip/hip_runtime.h>
#include <hip/hip_cooperative_groups.h>
#include <math.h>

namespace cg = cooperative_groups;

#define B_N   128
#define M_N   248
#define C_N   248
#define NODES 256
#define NT    (B_N*NODES)     // 32,768
#define NG    (B_N*M_N*C_N)   // 7,872,512

#define GRID  512             // 2 blocks/CU -> matches allocator's 2-block VGPR heuristic (128 regs @ TPB=512)
#define TPB   512             // 8 waves
#define WAVES 8
#define QROWS 62              // rows per block (quarter batch; 4 blocks/batch)
#define KMAX  8               // row slot k of a wave: i = q*62 + wave + 8*k
#define SLICES 32             // gTv slices per batch: 4 quarters * 8 waves
#define DYN_LDS (KMAX*TPB*16) // vG: [KMAX][TPB] float4 = 65536 B

#define PI_F     3.14159265358979323846f
#define INV_BM   (1.0f/31744.0f)
#define INV_BMC  (1.0f/7872512.0f)

__device__ __forceinline__ float rcp_nr(float x) {
    float r = __builtin_amdgcn_rcpf(x);
    return r * fmaf(-x, r, 2.0f);           // one NR step: ~fp32-accurate
}
__device__ __forceinline__ float sigm_fast(float x) {
    return rcp_nr(1.0f + __expf(-x));
}
__device__ __forceinline__ float sigm(float x) {   // precise (fallback path)
    float z = expf(-fabsf(x));
    return (x >= 0.0f) ? 1.0f/(1.0f+z) : z/(1.0f+z);
}
__device__ __forceinline__ float sgn(float x) {
    return (x > 0.0f) ? 1.0f : ((x < 0.0f) ? -1.0f : 0.0f);
}

// ===================== persistent cooperative path =====================
// 512 blocks x 512 threads (2 blocks/CU — the allocator's assumed occupancy,
// which empirically yields a 128-VGPR budget at TPB=512). Per-thread state:
// Gl+m as 16 explicit float4 variables (64 VGPRs), v in 64 KiB dynamic LDS.
// 64 state + ~35 temps < 128 -> no scratch spill (r3/r4/r5 failure mode).
extern __shared__ float4 vG_lds[];

__global__ __launch_bounds__(TPB, 2)
void persist_kernel(
    const float* __restrict__ adj, const float* __restrict__ Gl0,
    const float* __restrict__ T0,
    float* __restrict__ gTu,    // [2][B_N][M_N]
    float* __restrict__ gTv,    // [2][B_N*SLICES][256]  slice = b*32 + q*8 + wave
    float* __restrict__ accum,  // [2]
    float* __restrict__ out)    // [3]
{
    __shared__ float T_lds[NODES], mT_lds[NODES], vT_lds[NODES];
    __shared__ float red[2*WAVES];

    cg::grid_group grid = cg::this_grid();
    const int tid  = threadIdx.x;
    const int blkI = blockIdx.x;
    // XCD swizzle: the 4 blocks of a batch share low-3 bits (same XCD slot)
    const int b    = ((blkI >> 5) << 3) | (blkI & 7);
    const int q    = (blkI >> 3) & 3;    // quarter (rows q*62 .. q*62+61)
    const int wave = tid >> 6, lane = tid & 63;
    const bool v62 = (lane < 62);            // lane owns cols 4*lane..4*lane+3
    const int jb   = v62 ? 4*lane : 0;
    const int iBase = q*QROWS + wave;        // row for slot k: iBase + 8*k
    const float* adjRow0 = adj + ((size_t)(b*NODES + iBase))*NODES + 8 + jb;

    // slot k valid iff wave + 8k < 62: k<7 always (wave+48<=55), k==7 iff wave<6
    #define ROW_OK(k) ((k) < 7 || wave < 6)

    if (tid < NODES) {
        T_lds[tid]  = T0[b*NODES + tid];
        mT_lds[tid] = 0.0f;
        vT_lds[tid] = 0.0f;
    }
    #pragma unroll
    for (int k = 0; k < KMAX; ++k)
        vG_lds[k*TPB + tid] = float4{0.0f, 0.0f, 0.0f, 0.0f};

    float4 gl0, gl1, gl2, gl3, gl4, gl5, gl6, gl7;
    float4 mm0, mm1, mm2, mm3, mm4, mm5, mm6, mm7;
    #define LOADG(k, glv, mmv) do {                                               \
        glv = float4{0.0f,0.0f,0.0f,0.0f}; mmv = float4{0.0f,0.0f,0.0f,0.0f};     \
        if (ROW_OK(k) && v62)                                                     \
            glv = *(const float4*)&Gl0[((size_t)(b*M_N + iBase + 8*(k)))*C_N + jb]; \
    } while (0)
    LOADG(0, gl0, mm0); LOADG(1, gl1, mm1); LOADG(2, gl2, mm2); LOADG(3, gl3, mm3);
    LOADG(4, gl4, mm4); LOADG(5, gl5, mm5); LOADG(6, gl6, mm6); LOADG(7, gl7, mm7);
    #undef LOADG
    __syncthreads();

    double pw1d = 1.0, pw2d = 1.0;   // 0.9^(t-1), 0.999^(t-1)
    #pragma unroll 1
    for (int t = 1; t <= 200; ++t) {
        const float bc1p = (float)(1.0 - pw1d), bc2p = (float)(1.0 - pw2d);
        pw1d *= 0.9; pw2d *= 0.999;
        const float bc1 = (float)(1.0 - pw1d), bc2 = (float)(1.0 - pw2d);
        const float ibc1 = 1.0f/bc1, ibc2 = 1.0f/bc2;
        const int pw = t & 1, ps = (t-1) & 1;

        if (t > 1) {                 // grid-uniform
            grid.sync();
            if (tid < NODES) {       // T Adam update for step t-1 (redundant/block)
                float g = 0.0f;
                if (tid < M_N) g += gTu[ps*(B_N*M_N) + b*M_N + tid];
                if (tid >= 8) {
                    const float* gp = gTv + (size_t)ps*(B_N*SLICES*256)
                                    + (size_t)(b*SLICES)*256 + (tid-8);
                    float s = 0.0f;
                    #pragma unroll
                    for (int p = 0; p < SLICES; ++p) s += gp[p*256];
                    g -= s;
                }
                g *= INV_BMC;
                float m_ = 0.9f*mT_lds[tid] + 0.1f*g;
                float v_ = 0.999f*vT_lds[tid] + 0.001f*(g*g);
                mT_lds[tid] = m_; vT_lds[tid] = v_;
                T_lds[tid] = T_lds[tid] - 0.1f*(m_/bc1p)/(sqrtf(v_/bc2p) + 1e-8f);
            }
            __syncthreads();
        }

        const float Tv0 = T_lds[jb+8],  Tv1 = T_lds[jb+9];
        const float Tv2 = T_lds[jb+10], Tv3 = T_lds[jb+11];
        float av0 = 0.0f, av1 = 0.0f, av2 = 0.0f, av3 = 0.0f;

        #define DO_SLOT(Gx, ax, px, mx, vx) do {                                     \
            float dG  = coefP*(ax) + (px)*INV_BMC + 0.1f*INV_BMC*sgn((Gx)-0.5f);     \
            float grd = dG * (Gx) * (1.0f - (Gx));                                   \
            float m_ = 0.9f*(mx) + 0.1f*grd;                                         \
            float v_ = 0.999f*(vx) + 0.001f*(grd*grd);                               \
            (mx) = m_; (vx) = v_;                                                    \
            glslot -= 0.1f*(m_*ibc1)*rcp_nr(sqrtf(v_*ibc2) + 1e-8f);                 \
        } while (0)

        #define ROW_STEP(k, glv, mmv) do { if (ROW_OK(k)) {                          \
            const int i = iBase + 8*(k);                                             \
            float4 a4 = float4{0.0f,0.0f,0.0f,0.0f};                                 \
            if (v62) a4 = *(const float4*)(adjRow0 + (size_t)(8*(k))*NODES);         \
            const float G0 = sigm_fast(glv.x), G1 = sigm_fast(glv.y);                \
            const float G2 = sigm_fast(glv.z), G3 = sigm_fast(glv.w);                \
            const float Tu = T_lds[i];                                               \
            float d0, d1, d2, d3;                                                    \
            if (v62) { d0 = Tu-Tv0+0.1f; d1 = Tu-Tv1+0.1f;                           \
                       d2 = Tu-Tv2+0.1f; d3 = Tu-Tv3+0.1f; }                         \
            else     { d0 = d1 = d2 = d3 = 0.0f; }                                   \
            const float p0 = fmaxf(d0,0.0f), p1 = fmaxf(d1,0.0f);                    \
            const float p2 = fmaxf(d2,0.0f), p3 = fmaxf(d3,0.0f);                    \
            const float mk0 = (d0>0.0f)?1.0f:0.0f, mk1 = (d1>0.0f)?1.0f:0.0f;        \
            const float mk2 = (d2>0.0f)?1.0f:0.0f, mk3 = (d3>0.0f)?1.0f:0.0f;        \
            float sp = a4.x*G0 + a4.y*G1 + a4.z*G2 + a4.w*G3;                        \
            float gu = G0*mk0 + G1*mk1 + G2*mk2 + G3*mk3;                            \
            sp += __shfl_xor(sp,32,64); gu += __shfl_xor(gu,32,64);                  \
            sp += __shfl_xor(sp,16,64); gu += __shfl_xor(gu,16,64);                  \
            sp += __shfl_xor(sp, 8,64); gu += __shfl_xor(gu, 8,64);                  \
            sp += __shfl_xor(sp, 4,64); gu += __shfl_xor(gu, 4,64);                  \
            sp += __shfl_xor(sp, 2,64); gu += __shfl_xor(gu, 2,64);                  \
            sp += __shfl_xor(sp, 1,64); gu += __shfl_xor(gu, 1,64);                  \
            av0 += G0*mk0; av1 += G1*mk1; av2 += G2*mk2; av3 += G3*mk3;              \
            const float half_arg = (PI_F*sp)*0.5f;                                   \
            const float sv = __sinf(half_arg), cv = __cosf(half_arg);                \
            const float coefP = 2.0f*(sv*sv-1.0f)*sv*cv*PI_F*INV_BM;                 \
            if (lane == 0) gTu[pw*(B_N*M_N) + b*M_N + i] = gu;                       \
            float4 vv = vG_lds[(k)*TPB + tid];                                       \
            { float& glslot = glv.x; DO_SLOT(G0, a4.x, p0, mmv.x, vv.x); }           \
            { float& glslot = glv.y; DO_SLOT(G1, a4.y, p1, mmv.y, vv.y); }           \
            { float& glslot = glv.z; DO_SLOT(G2, a4.z, p2, mmv.z, vv.z); }           \
            { float& glslot = glv.w; DO_SLOT(G3, a4.w, p3, mmv.w, vv.w); }           \
            vG_lds[(k)*TPB + tid] = vv;                                              \
        } } while (0)

        ROW_STEP(0, gl0, mm0); ROW_STEP(1, gl1, mm1);
        ROW_STEP(2, gl2, mm2); ROW_STEP(3, gl3, mm3);
        ROW_STEP(4, gl4, mm4); ROW_STEP(5, gl5, mm5);
        ROW_STEP(6, gl6, mm6); ROW_STEP(7, gl7, mm7);
        #undef ROW_STEP
        #undef DO_SLOT

        // per-wave gTv column-partial slice (lanes 62/63 carry zeros)
        {
            float* gpw = gTv + (size_t)pw*(B_N*SLICES*256)
                       + (size_t)(b*SLICES + q*WAVES + wave)*256;
            ((float4*)gpw)[lane] = float4{av0, av1, av2, av3};
        }
    }

    // ---------------- final T update (step 200; parity slot 0) ----------------
    grid.sync();
    if (tid < NODES) {
        const float bc1p = (float)(1.0 - pw1d), bc2p = (float)(1.0 - pw2d);
        float g = 0.0f;
        if (tid < M_N) g += gTu[0*(B_N*M_N) + b*M_N + tid];
        if (tid >= 8) {
            const float* gp = gTv + (size_t)(b*SLICES)*256 + (tid-8);
            float s = 0.0f;
            #pragma unroll
            for (int p = 0; p < SLICES; ++p) s += gp[p*256];
            g -= s;
        }
        g *= INV_BMC;
        float m_ = 0.9f*mT_lds[tid] + 0.1f*g;
        float v_ = 0.999f*vT_lds[tid] + 0.001f*(g*g);
        T_lds[tid] = T_lds[tid] - 0.1f*(m_/bc1p)/(sqrtf(v_/bc2p) + 1e-8f);
    }
    __syncthreads();

    // ---------------- final losses ----------------
    {
        const float Tv0 = T_lds[jb+8],  Tv1 = T_lds[jb+9];
        const float Tv2 = T_lds[jb+10], Tv3 = T_lds[jb+11];
        float pacc = 0.0f, cacc = 0.0f;

        #define ROW_LOSS(k, glv) do { if (ROW_OK(k)) {                               \
            const int i = iBase + 8*(k);                                             \
            float4 a4 = float4{0.0f,0.0f,0.0f,0.0f};                                 \
            if (v62) a4 = *(const float4*)(adjRow0 + (size_t)(8*(k))*NODES);         \
            const float G0 = sigm_fast(glv.x), G1 = sigm_fast(glv.y);                \
            const float G2 = sigm_fast(glv.z), G3 = sigm_fast(glv.w);                \
            const float Tu = T_lds[i];                                               \
            const float p0 = v62 ? fmaxf(Tu-Tv0+0.1f, 0.0f) : 0.0f;                  \
            const float p1 = v62 ? fmaxf(Tu-Tv1+0.1f, 0.0f) : 0.0f;                  \
            const float p2 = v62 ? fmaxf(Tu-Tv2+0.1f, 0.0f) : 0.0f;                  \
            const float p3 = v62 ? fmaxf(Tu-Tv3+0.1f, 0.0f) : 0.0f;                  \
            float sp = a4.x*G0 + a4.y*G1 + a4.z*G2 + a4.w*G3;                        \
            float cp = G0*p0 + G1*p1 + G2*p2 + G3*p3;                                \
            sp += __shfl_xor(sp,32,64); cp += __shfl_xor(cp,32,64);                  \
            sp += __shfl_xor(sp,16,64); cp += __shfl_xor(cp,16,64);                  \
            sp += __shfl_xor(sp, 8,64); cp += __shfl_xor(cp, 8,64);                  \
            sp += __shfl_xor(sp, 4,64); cp += __shfl_xor(cp, 4,64);                  \
            sp += __shfl_xor(sp, 2,64); cp += __shfl_xor(cp, 2,64);                  \
            sp += __shfl_xor(sp, 1,64); cp += __shfl_xor(cp, 1,64);                  \
            if (lane == 0) {                                                         \
                const float sv = sinf((PI_F*sp)*0.5f);                               \
                const float dd = sv*sv - 1.0f;                                       \
                pacc += dd*dd;                                                       \
                cacc += cp;                                                          \
            }                                                                        \
        } } while (0)

        ROW_LOSS(0, gl0); ROW_LOSS(1, gl1); ROW_LOSS(2, gl2); ROW_LOSS(3, gl3);
        ROW_LOSS(4, gl4); ROW_LOSS(5, gl5); ROW_LOSS(6, gl6); ROW_LOSS(7, gl7);
        #undef ROW_LOSS

        if (lane == 0) { red[wave] = pacc; red[WAVES+wave] = cacc; }
    }
    __syncthreads();
    if (tid == 0) {
        float rp = 0.0f, rc = 0.0f;
        #pragma unroll
        for (int w = 0; w < WAVES; ++w) { rp += red[w]; rc += red[WAVES+w]; }
        atomicAdd(&accum[0], rp);
        atomicAdd(&accum[1], rc);
    }
    __threadfence();
    grid.sync();
    if (blkI == 0 && tid == 0) {
        const float p = __hip_atomic_load(&accum[0], __ATOMIC_RELAXED, __HIP_MEMORY_SCOPE_AGENT) * INV_BM;
        const float c = __hip_atomic_load(&accum[1], __ATOMIC_RELAXED, __HIP_MEMORY_SCOPE_AGENT) * INV_BMC;
        out[0] = p + c;
        out[1] = p;
        out[2] = c;
    }
    #undef ROW_OK
}

// ===================== fallback multi-launch path (round-1, known-good) =====================
#define NBLK  8
#define RPB   31

__global__ __launch_bounds__(256) void iter_kernel(
    const float* __restrict__ adj, float* __restrict__ Gl,
    float* __restrict__ mG, float* __restrict__ vG,
    float* __restrict__ T_state, float* __restrict__ mT, float* __restrict__ vT,
    float* __restrict__ gTu, float* __restrict__ gTv,
    int t, float bc1p, float bc2p, float bc1, float bc2)
{
    __shared__ float T_lds[NODES];
    __shared__ float gv_lds[4*NODES];
    const int tid = threadIdx.x;
    const int b   = blockIdx.x >> 3;
    const int blk = blockIdx.x & 7;

    if (t == 1) {
        T_lds[tid] = T_state[b*NODES + tid];
    } else {
        const int rs = t & 1, ws2 = (t+1) & 1, ps = (t-1) & 1;
        const int idx = b*NODES + tid;
        float Tval = T_state[rs*NT + idx];
        float g = 0.0f;
        if (tid < M_N) g += gTu[ps*(B_N*M_N) + b*M_N + tid];
        if (tid >= 8) {
            const float* gp = gTv + (size_t)ps*(B_N*NBLK*C_N) + (size_t)b*NBLK*C_N + (tid-8);
            float s = 0.0f;
            #pragma unroll
            for (int k = 0; k < NBLK; ++k) s += gp[k*C_N];
            g -= s;
        }
        g *= INV_BMC;
        float m_ = 0.9f*mT[rs*NT+idx] + 0.1f*g;
        float v_ = 0.999f*vT[rs*NT+idx] + 0.001f*(g*g);
        float newT = Tval - 0.1f*(m_/bc1p)/(sqrtf(v_/bc2p) + 1e-8f);
        T_state[ws2*NT+idx] = newT;
        mT[ws2*NT+idx] = m_;
        vT[ws2*NT+idx] = v_;
        T_lds[tid] = newT;
    }
    gv_lds[tid] = 0.0f; gv_lds[256+tid] = 0.0f; gv_lds[512+tid] = 0.0f; gv_lds[768+tid] = 0.0f;
    __syncthreads();

    const int wave = tid >> 6, lane = tid & 63;
    const int pw = t & 1;
    const int j0 = lane, j1 = lane+64, j2 = lane+128, j3 = lane+192;
    const bool v3 = (lane < 56);
    float av0 = 0.0f, av1 = 0.0f, av2 = 0.0f, av3 = 0.0f;

    for (int r = wave; r < RPB; r += 4) {
        const int i = blk*RPB + r;
        const size_t arow = ((size_t)(b*NODES + i))*NODES + 8;
        const size_t grow = ((size_t)(b*M_N + i))*C_N;

        float gl0 = Gl[grow+j0], gl1 = Gl[grow+j1], gl2 = Gl[grow+j2];
        float gl3 = v3 ? Gl[grow+j3] : 0.0f;
        float a0 = adj[arow+j0], a1 = adj[arow+j1], a2 = adj[arow+j2];
        float a3 = v3 ? adj[arow+j3] : 0.0f;
        float G0 = sigm(gl0), G1 = sigm(gl1), G2 = sigm(gl2), G3 = sigm(gl3);

        float Tu = T_lds[i];
        float d0 = Tu - T_lds[j0+8] + 0.1f;
        float d1 = Tu - T_lds[j1+8] + 0.1f;
        float d2 = Tu - T_lds[j2+8] + 0.1f;
        float d3 = v3 ? (Tu - T_lds[j3+8] + 0.1f) : 0.0f;
        float p0 = fmaxf(d0, 0.0f), p1 = fmaxf(d1, 0.0f);
        float p2 = fmaxf(d2, 0.0f), p3 = fmaxf(d3, 0.0f);
        float mk0 = (d0 > 0.0f) ? 1.0f : 0.0f;
        float mk1 = (d1 > 0.0f) ? 1.0f : 0.0f;
        float mk2 = (d2 > 0.0f) ? 1.0f : 0.0f;
        float mk3 = (v3 && d3 > 0.0f) ? 1.0f : 0.0f;

        float sp = a0*G0 + a1*G1 + a2*G2 + (v3 ? a3*G3 : 0.0f);
        float gu = G0*mk0 + G1*mk1 + G2*mk2 + G3*mk3;
        #pragma unroll
        for (int off = 32; off > 0; off >>= 1) {
            sp += __shfl_xor(sp, off, 64);
            gu += __shfl_xor(gu, off, 64);
        }
        av0 += G0*mk0; av1 += G1*mk1; av2 += G2*mk2; av3 += G3*mk3;

        float half_arg = (PI_F*sp)*0.5f;
        float sv = sinf(half_arg), cv = cosf(half_arg);
        float val = sv*sv;
        float coefP = 2.0f*(val-1.0f)*sv*cv*PI_F*INV_BM;

        if (lane == 0) gTu[pw*(B_N*M_N) + b*M_N + i] = gu;

        #define DO_SLOT(Gx, glx, ax, px, jx, valid) do { if (valid) {            \
            float dG  = coefP*(ax) + (px)*INV_BMC + 0.1f*INV_BMC*sgn((Gx)-0.5f); \
            float grd = dG * (Gx) * (1.0f - (Gx));                               \
            float m_ = 0.9f*mG[grow+(jx)] + 0.1f*grd;                            \
            float v_ = 0.999f*vG[grow+(jx)] + 0.001f*(grd*grd);                  \
            mG[grow+(jx)] = m_; vG[grow+(jx)] = v_;                              \
            Gl[grow+(jx)] = (glx) - 0.1f*(m_/bc1)/(sqrtf(v_/bc2)+1e-8f);         \
        } } while (0)
        DO_SLOT(G0, gl0, a0, p0, j0, true);
        DO_SLOT(G1, gl1, a1, p1, j1, true);
        DO_SLOT(G2, gl2, a2, p2, j2, true);
        DO_SLOT(G3, gl3, a3, p3, j3, v3);
        #undef DO_SLOT
    }

    gv_lds[wave*256 + j0] = av0;
    gv_lds[wave*256 + j1] = av1;
    gv_lds[wave*256 + j2] = av2;
    if (v3) gv_lds[wave*256 + j3] = av3;
    __syncthreads();
    if (tid < C_N) {
        float s = gv_lds[tid] + gv_lds[256+tid] + gv_lds[512+tid] + gv_lds[768+tid];
        gTv[(size_t)pw*(B_N*NBLK*C_N) + (size_t)(b*NBLK + blk)*C_N + tid] = s;
    }
}

__global__ __launch_bounds__(256) void t_fin_kernel(
    float* __restrict__ T_state, const float* __restrict__ mT, const float* __restrict__ vT,
    const float* __restrict__ gTu, const float* __restrict__ gTv,
    float bc1p, float bc2p)
{
    const int b = blockIdx.x, tid = threadIdx.x;
    const int idx = b*NODES + tid;
    float Tval = T_state[1*NT + idx];
    float g = 0.0f;
    if (tid < M_N) g += gTu[0*(B_N*M_N) + b*M_N + tid];
    if (tid >= 8) {
        const float* gp = gTv + (size_t)b*NBLK*C_N + (tid-8);
        float s = 0.0f;
        #pragma unroll
        for (int k = 0; k < NBLK; ++k) s += gp[k*C_N];
        g -= s;
    }
    g *= INV_BMC;
    float m_ = 0.9f*mT[1*NT+idx] + 0.1f*g;
    float v_ = 0.999f*vT[1*NT+idx] + 0.001f*(g*g);
    T_state[0*NT+idx] = Tval - 0.1f*(m_/bc1p)/(sqrtf(v_/bc2p) + 1e-8f);
}

__global__ __launch_bounds__(256) void loss_kernel(
    const float* __restrict__ adj, const float* __restrict__ Gl,
    const float* __restrict__ T_state, float* __restrict__ accum)
{
    __shared__ float T_lds[NODES];
    __shared__ float red[8];
    const int tid = threadIdx.x;
    const int b = blockIdx.x >> 3, blk = blockIdx.x & 7;
    T_lds[tid] = T_state[b*NODES + tid];
    __syncthreads();
    const int wave = tid >> 6, lane = tid & 63;
    const int j0 = lane, j1 = lane+64, j2 = lane+128, j3 = lane+192;
    const bool v3 = (lane < 56);
    float pacc = 0.0f, cacc = 0.0f;

    for (int r = wave; r < RPB; r += 4) {
        const int i = blk*RPB + r;
        const size_t arow = ((size_t)(b*NODES + i))*NODES + 8;
        const size_t grow = ((size_t)(b*M_N + i))*C_N;
        float gl0 = Gl[grow+j0], gl1 = Gl[grow+j1], gl2 = Gl[grow+j2];
        float gl3 = v3 ? Gl[grow+j3] : 0.0f;
        float a0 = adj[arow+j0], a1 = adj[arow+j1], a2 = adj[arow+j2];
        float a3 = v3 ? adj[arow+j3] : 0.0f;
        float G0 = sigm(gl0), G1 = sigm(gl1), G2 = sigm(gl2), G3 = sigm(gl3);

        float Tu = T_lds[i];
        float p0 = fmaxf(Tu - T_lds[j0+8] + 0.1f, 0.0f);
        float p1 = fmaxf(Tu - T_lds[j1+8] + 0.1f, 0.0f);
        float p2 = fmaxf(Tu - T_lds[j2+8] + 0.1f, 0.0f);
        float p3 = v3 ? fmaxf(Tu - T_lds[j3+8] + 0.1f, 0.0f) : 0.0f;

        float sp = a0*G0 + a1*G1 + a2*G2 + (v3 ? a3*G3 : 0.0f);
        float cp = G0*p0 + G1*p1 + G2*p2 + (v3 ? G3*p3 : 0.0f);
        #pragma unroll
        for (int off = 32; off > 0; off >>= 1) {
            sp += __shfl_xor(sp, off, 64);
            cp += __shfl_xor(cp, off, 64);
        }
        if (lane == 0) {
            float sv = sinf((PI_F*sp)*0.5f);
            float dd = sv*sv - 1.0f;
            pacc += dd*dd;
            cacc += cp;
        }
    }
    if (lane == 0) { red[wave] = pacc; red[4+wave] = cacc; }
    __syncthreads();
    if (tid == 0) {
        atomicAdd(&accum[0], red[0]+red[1]+red[2]+red[3]);
        atomicAdd(&accum[1], red[4]+red[5]+red[6]+red[7]);
    }
}

__global__ void finish_kernel(const float* __restrict__ accum, float* __restrict__ out) {
    if (threadIdx.x == 0 && blockIdx.x == 0) {
        float p = accum[0] / 31744.0f;
        float c = accum[1] / 7872512.0f;
        out[0] = p + c;
        out[1] = p;
        out[2] = c;
    }
}

extern "C" void kernel_launch(void* const* d_in, const int* in_sizes, int n_in,
                              void* d_out, int out_size, void* d_ws, size_t ws_size,
                              hipStream_t stream) {
    const float* adj = (const float*)d_in[0];
    float* Gl        = (float*)d_in[1];
    const float* T0  = (const float*)d_in[2];
    float* out       = (float*)d_out;
    float* ws        = (float*)d_ws;

    // host-side gate (pure host queries + func attribute; capture-safe)
    int dev = 0;  hipGetDevice(&dev);
    int numCU = 0;
    hipDeviceGetAttribute(&numCU, hipDeviceAttributeMultiprocessorCount, dev);
    hipError_t aerr = hipFuncSetAttribute((const void*)persist_kernel,
                                          hipFuncAttributeMaxDynamicSharedMemorySize,
                                          DYN_LDS);
    int maxB = 0;
    hipError_t oerr = hipOccupancyMaxActiveBlocksPerMultiprocessor(
                          &maxB, persist_kernel, TPB, DYN_LDS);
    const bool coop_ok = (aerr == hipSuccess) && (oerr == hipSuccess) &&
                         (maxB >= 1) && ((long)maxB * (long)numCU >= GRID);

    if (coop_ok) {
        float* gTu   = ws;                               // 2*128*248
        float* gTv   = gTu + 2*B_N*M_N;                  // 2*128*32*256
        float* accum = gTv + (size_t)2*B_N*SLICES*256;   // 2
        hipMemsetAsync(accum, 0, 2*sizeof(float), stream);

        const float* Gl0 = Gl;
        void* args[] = { (void*)&adj, (void*)&Gl0, (void*)&T0,
                         (void*)&gTu, (void*)&gTv, (void*)&accum, (void*)&out };
        hipLaunchCooperativeKernel((void*)persist_kernel,
                                   dim3(GRID), dim3(TPB), args, DYN_LDS, stream);
    } else {
        float* mG      = ws;
        float* vG      = mG + NG;
        float* T_state = vG + NG;
        float* mT      = T_state + 2*NT;
        float* vT      = mT + 2*NT;
        float* gTu     = vT + 2*NT;
        float* gTv     = gTu + 2*B_N*M_N;
        float* accum   = gTv + (size_t)2*B_N*NBLK*C_N;

        hipMemsetAsync(mG, 0, (size_t)2*NG*sizeof(float), stream);
        hipMemsetAsync(mT, 0, (size_t)4*NT*sizeof(float), stream);
        hipMemsetAsync(accum, 0, 2*sizeof(float), stream);
        hipMemcpyAsync(T_state, T0, NT*sizeof(float), hipMemcpyDeviceToDevice, stream);

        for (int t = 1; t <= 200; ++t) {
            float bc1p = 1.0f - (float)pow(0.9,   (double)(t-1));
            float bc2p = 1.0f - (float)pow(0.999, (double)(t-1));
            float bc1  = 1.0f - (float)pow(0.9,   (double)t);
            float bc2  = 1.0f - (float)pow(0.999, (double)t);
            iter_kernel<<<dim3(B_N*NBLK), dim3(256), 0, stream>>>(
                adj, Gl, mG, vG, T_state, mT, vT, gTu, gTv, t, bc1p, bc2p, bc1, bc2);
        }
        {
            float bc1p = 1.0f - (float)pow(0.9,   200.0);
            float bc2p = 1.0f - (float)pow(0.999, 200.0);
            t_fin_kernel<<<dim3(B_N), dim3(256), 0, stream>>>(T_state, mT, vT, gTu, gTv, bc1p, bc2p);
        }
        loss_kernel<<<dim3(B_N*NBLK), dim3(256), 0, stream>>>(adj, Gl, T_state, accum);
        finish_kernel<<<1, 64, 0, stream>>>(accum, out);
    }
}